// Round 2
// baseline (504.543 us; speedup 1.0000x reference)
//
#include <hip/hip_runtime.h>

// Problem constants
#define Bn   4
#define Cc   256
#define Hh   128
#define Ww   256
#define HWp  32768          // H*W
#define CQK  64
#define COUT 256

typedef _Float16 half8 __attribute__((ext_vector_type(8)));
typedef _Float16 half4 __attribute__((ext_vector_type(4)));
typedef float   floatx4  __attribute__((ext_vector_type(4)));
typedef float   floatx16 __attribute__((ext_vector_type(16)));

#define MFMA16(a, b, c) __builtin_amdgcn_mfma_f32_16x16x32_f16((a), (b), (c), 0, 0, 0)
#define MFMA32(a, b, c) __builtin_amdgcn_mfma_f32_32x32x16_f16((a), (b), (c), 0, 0, 0)

// ---------------------------------------------------------------------------
// Kernel 1: Q/K/V 1x1-conv projections (fp32 NCHW inputs -> f16 ws tensors)
//   Qws, Kws: pixel-major [b][pix][64]   (pix = h*W + w)
//   Vws:      channel-major [b][o][pix]
// grid: (512 pixel-tiles of 64, B, 2 jobs: 0=Q from de_out, 1=K+V from flow)
// Weights live in registers (A-frags from global); only X goes through LDS.
// One barrier per block.
// ---------------------------------------------------------------------------
__global__ __launch_bounds__(256, 4) void k_qkv(
    const float* __restrict__ flow, const float* __restrict__ de_out,
    const float* __restrict__ Wq, const float* __restrict__ bq,
    const float* __restrict__ Wk, const float* __restrict__ bk,
    const float* __restrict__ Wv, const float* __restrict__ bv,
    _Float16* __restrict__ Qws, _Float16* __restrict__ Kws,
    _Float16* __restrict__ Vws)
{
    __shared__ __align__(16) _Float16 x_lds[64 * 264];  // [px][c], pitch 264

    const int t   = threadIdx.x;
    const int b   = blockIdx.y;
    const int job = blockIdx.z;
    const int pb  = blockIdx.x * 64;  // pixel base in [0, HW)

    const float* X = (job == 0 ? de_out : flow) + (size_t)b * Cc * HWp;

    // ---- stage X tile transposed: lane writes half8 ALONG c (conflict-free)
    {
        const int px4 = t & 15;   // pixel quad 0..15
        const int c8  = t >> 4;   // 0..15 -> c base 8*c8 (+128 per rep)
        for (int rep = 0; rep < 2; ++rep) {
            const int c0 = 8 * c8 + 128 * rep;
            float4 r[8];
            #pragma unroll
            for (int j = 0; j < 8; ++j)
                r[j] = *(const float4*)&X[(size_t)(c0 + j) * HWp + pb + 4 * px4];
            #pragma unroll
            for (int i = 0; i < 4; ++i) {
                half8 h;
                #pragma unroll
                for (int j = 0; j < 8; ++j) h[j] = (_Float16)((&r[j].x)[i]);
                *(half8*)&x_lds[(4 * px4 + i) * 264 + c0] = h;
            }
        }
    }
    __syncthreads();

    const int wv   = t >> 6;
    const int lane = t & 63;
    const int quad = lane >> 4;
    const int l16  = lane & 15;
    const int ntiles = (job == 0) ? 1 : 5;

    for (int tt = 0; tt < ntiles; ++tt) {
        const float* Wsel; const float* bsel; _Float16* dst; int m0, mode;
        if (job == 0)    { Wsel = Wq; bsel = bq; dst = Qws; m0 = 16 * wv;              mode = 0; }
        else if (tt==0)  { Wsel = Wk; bsel = bk; dst = Kws; m0 = 16 * wv;              mode = 0; }
        else             { Wsel = Wv; bsel = bv; dst = Vws; m0 = 64 * (tt-1) + 16*wv;  mode = 1; }

        // A-frags: row m0+l16, k = ks*32 + quad*8 .. +8 (fp32 global -> f16 regs)
        half8 a[8];
        const float* wrow = &Wsel[(size_t)(m0 + l16) * 256];
        #pragma unroll
        for (int ks = 0; ks < 8; ++ks) {
            float4 wa = *(const float4*)&wrow[ks * 32 + quad * 8];
            float4 wb = *(const float4*)&wrow[ks * 32 + quad * 8 + 4];
            a[ks] = (half8){(_Float16)wa.x, (_Float16)wa.y, (_Float16)wa.z, (_Float16)wa.w,
                            (_Float16)wb.x, (_Float16)wb.y, (_Float16)wb.z, (_Float16)wb.w};
        }
        float4 bi = *(const float4*)&bsel[m0 + quad * 4];
        const float bia[4] = {bi.x, bi.y, bi.z, bi.w};

        #pragma unroll
        for (int nt = 0; nt < 4; ++nt) {
            floatx4 acc = {0.f, 0.f, 0.f, 0.f};
            #pragma unroll
            for (int ks = 0; ks < 8; ++ks) {
                half8 bf = *(const half8*)&x_lds[(nt * 16 + l16) * 264 + ks * 32 + quad * 8];
                acc = MFMA16(a[ks], bf, acc);
            }
            const int pix = pb + nt * 16 + l16;
            if (mode == 0) {
                // D: row = quad*4+r (channel), col = l16 (pixel)
                half4 h = (half4){(_Float16)(acc[0] + bia[0]), (_Float16)(acc[1] + bia[1]),
                                  (_Float16)(acc[2] + bia[2]), (_Float16)(acc[3] + bia[3])};
                *(half4*)&dst[((size_t)b * HWp + pix) * 64 + m0 + quad * 4] = h;
            } else {
                #pragma unroll
                for (int r = 0; r < 4; ++r) {
                    const int o = m0 + quad * 4 + r;
                    dst[((size_t)b * 256 + o) * HWp + pix] = (_Float16)(acc[r] + bia[r]);
                }
            }
        }
    }
}

// ---------------------------------------------------------------------------
// Kernel 2: width-axial attention per (b,h) row, 32x32x16 MFMA.
// grid (H, B), 256 thr, ~69 KB LDS -> 2 blocks/CU.
// 4 chunks of 64 queries: stage K -> energy -> softmax -> PV with att
// B-frags in registers across the os-loop (only v read from LDS).
// ---------------------------------------------------------------------------
__global__ __launch_bounds__(256, 2) void k_attn(
    const _Float16* __restrict__ Qws, const _Float16* __restrict__ Kws,
    const _Float16* __restrict__ Vws, float* __restrict__ out)
{
    __shared__ __align__(16) _Float16 kv_lds[256 * 72];   // k:[w'][d] p72  / v:[o][w'] p264 (64 rows)
    __shared__ __align__(16) _Float16 att_lds[64 * 264];  // [w][w'] pitch 264
    __shared__ float inv_l[64];

    const int t    = threadIdx.x;
    const int h    = blockIdx.x;
    const int b    = blockIdx.y;
    const int wv   = t >> 6;
    const int lane = t & 63;
    const int hi   = lane >> 5;
    const int l32  = lane & 31;
    const size_t pixbase = (size_t)b * HWp + h * 256;

    for (int chunk = 0; chunk < 4; ++chunk) {
        __syncthreads();  // prev-chunk PV still reading kv_lds/att_lds
        // ---- stage K: 256 rows x 64 d
        #pragma unroll
        for (int i = 0; i < 8; ++i) {
            const int g = t + 256 * i;
            const int row = g >> 3, off = (g & 7) * 8;
            *(half8*)&kv_lds[row * 72 + off] =
                *(const half8*)&Kws[(pixbase + row) * 64 + off];
        }
        __syncthreads();

        // ---- energy 64x256: wave tile m32 = wv&1, n32 group = wv>>1 (4 tiles)
        {
            const int mt = wv & 1;
            half8 aq[4];
            #pragma unroll
            for (int ks = 0; ks < 4; ++ks)
                aq[ks] = *(const half8*)&Qws[(pixbase + chunk*64 + mt*32 + l32) * 64
                                             + ks * 16 + hi * 8];
            #pragma unroll
            for (int j = 0; j < 4; ++j) {
                const int n0 = (4 * (wv >> 1) + j) * 32;
                floatx16 acc = {};
                #pragma unroll
                for (int ks = 0; ks < 4; ++ks) {
                    half8 bk8 = *(const half8*)&kv_lds[(n0 + l32) * 72 + ks * 16 + hi * 8];
                    acc = MFMA32(aq[ks], bk8, acc);
                }
                #pragma unroll
                for (int r = 0; r < 16; ++r) {
                    const int row = mt * 32 + (r & 3) + 8 * (r >> 2) + 4 * hi;
                    att_lds[row * 264 + n0 + l32] = (_Float16)acc[r];
                }
            }
        }
        __syncthreads();

        // ---- softmax: 64 rows, 8 threads/row, 2 passes, fp32 math
        #pragma unroll
        for (int p = 0; p < 2; ++p) {
            const int row = 32 * p + (t >> 3), seg = t & 7;
            _Float16* rowp = &att_lds[row * 264 + seg * 32];
            float vals[32];
            float mx = -1e30f;
            #pragma unroll
            for (int i8 = 0; i8 < 4; ++i8) {
                half8 hv = *(const half8*)&rowp[i8 * 8];
                #pragma unroll
                for (int j = 0; j < 8; ++j) {
                    vals[i8 * 8 + j] = (float)hv[j];
                    mx = fmaxf(mx, vals[i8 * 8 + j]);
                }
            }
            mx = fmaxf(mx, __shfl_xor(mx, 1));
            mx = fmaxf(mx, __shfl_xor(mx, 2));
            mx = fmaxf(mx, __shfl_xor(mx, 4));
            float s = 0.f;
            #pragma unroll
            for (int i = 0; i < 32; ++i) { vals[i] = __expf(vals[i] - mx); s += vals[i]; }
            s += __shfl_xor(s, 1);
            s += __shfl_xor(s, 2);
            s += __shfl_xor(s, 4);
            #pragma unroll
            for (int i8 = 0; i8 < 4; ++i8) {
                half8 hv;
                #pragma unroll
                for (int j = 0; j < 8; ++j) hv[j] = (_Float16)vals[i8 * 8 + j];
                *(half8*)&rowp[i8 * 8] = hv;
            }
            if (seg == 0) inv_l[row] = 1.f / s;
        }
        __syncthreads();

        // ---- PV: wave (wt = w-tile, ot = o-subtile); att B-frags in regs
        const int wt = wv & 1, ot = wv >> 1;
        half8 batt[16];
        #pragma unroll
        for (int ks = 0; ks < 16; ++ks)
            batt[ks] = *(const half8*)&att_lds[(wt * 32 + l32) * 264 + ks * 16 + hi * 8];
        const float il = inv_l[wt * 32 + l32];

        for (int os = 0; os < 4; ++os) {
            __syncthreads();  // kv_lds: previous readers done
            #pragma unroll
            for (int i = 0; i < 8; ++i) {
                const int g = t + 256 * i;
                const int row = g >> 5, off = (g & 31) * 8;
                *(half8*)&kv_lds[row * 264 + off] =
                    *(const half8*)&Vws[((size_t)b * 256 + os * 64 + row) * HWp
                                        + h * 256 + off];
            }
            __syncthreads();

            floatx16 acc = {};
            #pragma unroll
            for (int ks = 0; ks < 16; ++ks) {
                half8 av = *(const half8*)&kv_lds[(ot * 32 + l32) * 264 + ks * 16 + hi * 8];
                acc = MFMA32(av, batt[ks], acc);
            }
            // D: col = l32 -> w, row = (r&3)+8*(r>>2)+4*hi -> o-local
            const int wgl = chunk * 64 + wt * 32 + l32;
            #pragma unroll
            for (int r = 0; r < 16; ++r) {
                const int o = os * 64 + ot * 32 + (r & 3) + 8 * (r >> 2) + 4 * hi;
                out[((size_t)(b * 256 + o) * Hh + h) * Ww + wgl] = acc[r] * il;
            }
        }
    }
}

// ---------------------------------------------------------------------------
extern "C" void kernel_launch(void* const* d_in, const int* in_sizes, int n_in,
                              void* d_out, int out_size, void* d_ws, size_t ws_size,
                              hipStream_t stream)
{
    const float* flow   = (const float*)d_in[0];
    const float* de_out = (const float*)d_in[1];
    const float* Wq = (const float*)d_in[2];
    const float* bq = (const float*)d_in[3];
    const float* Wk = (const float*)d_in[4];
    const float* bk = (const float*)d_in[5];
    const float* Wv = (const float*)d_in[6];
    const float* bv = (const float*)d_in[7];

    _Float16* Qws = (_Float16*)d_ws;
    _Float16* Kws = Qws + (size_t)Bn * HWp * 64;
    _Float16* Vws = Kws + (size_t)Bn * HWp * 64;
    float* out = (float*)d_out;

    dim3 g1(HWp / 64, Bn, 2);
    k_qkv<<<g1, 256, 0, stream>>>(flow, de_out, Wq, bq, Wk, bk, Wv, bv, Qws, Kws, Vws);

    dim3 g2(Hh, Bn);
    k_attn<<<g2, 256, 0, stream>>>(Qws, Kws, Vws, out);
}